// Round 11
// baseline (558.881 us; speedup 1.0000x reference)
//
#include <hip/hip_runtime.h>
#include <hip/hip_bf16.h>

#define N_NODES 100000
#define N_EDGES 1600000
#define N_GRAPHS 512
#define NTILES (N_NODES / 16)          // 6250, exact
#define BSH 9                          // 512 nodes per bucket
#define NBUCK ((N_NODES + 511) >> BSH) // 196
#define NB1 256                        // blocks for hist/scatter passes

typedef __hip_bfloat16 bf16;
typedef unsigned int uint;
typedef unsigned short ushort;
typedef __attribute__((ext_vector_type(8))) short short8;
typedef __attribute__((ext_vector_type(4))) float float4v;

__device__ __forceinline__ float b2f(bf16 v) { return __bfloat162float(v); }
__device__ __forceinline__ bf16 f2b(float v) { return __float2bfloat16(v); }
__device__ __forceinline__ short f2bs(float v) { bf16 h = f2b(v); return *(short*)&h; }

__device__ __forceinline__ float ldf(const void* p, long i, int isf32) {
    return isf32 ? ((const float*)p)[i] : b2f(((const bf16*)p)[i]);
}
__device__ __forceinline__ int geti(const int* p, long i, int is64) {
    return is64 ? p[2 * i] : p[i];
}
__device__ __forceinline__ float bflo(uint u) { return __uint_as_float(u << 16); }
__device__ __forceinline__ float bfhi(uint u) { return __uint_as_float(u & 0xffff0000u); }
__device__ __forceinline__ uint packbf(float x, float y) {
    bf16 a = f2b(x), b = f2b(y);
    ushort ua = *(ushort*)&a, ub = *(ushort*)&b;
    return (uint)ua | ((uint)ub << 16);
}

// ---------------- dtype detection ----------------
__global__ void k_detect(const void* __restrict__ x, const int* __restrict__ ei,
                         int* __restrict__ flags) {
    if (threadIdx.x != 0 || blockIdx.x != 0) return;
    const ushort* xu = (const ushort*)x;
    int plaus = 0;
    for (int i = 0; i < 256; i++) {
        ushort u = xu[2 * i];
        int e = (u >> 7) & 0xFF;
        if (u == 0 || (e >= 116 && e <= 132)) plaus++;
    }
    flags[0] = (plaus < 128) ? 1 : 0;          // 1 => fp32 inputs
    int nz = 0;
    for (int i = 0; i < 128; i++) if (ei[2 * i + 1] != 0) nz++;
    flags[1] = (nz < 8) ? 1 : 0;               // 1 => int64 indices
}

// ---------------- CSR build: deterministic 2-pass radix partition ----------------
__global__ __launch_bounds__(256) void k1_hist(const int* __restrict__ ei,
                                               const int* __restrict__ flags,
                                               int* __restrict__ hist) {
    __shared__ int h[NBUCK];
    int tid = threadIdx.x;
    for (int i = tid; i < NBUCK; i += 256) h[i] = 0;
    __syncthreads();
    int i64 = flags[1];
    for (int e = blockIdx.x * 256 + tid; e < N_EDGES; e += NB1 * 256) {
        int c = geti(ei, (long)N_EDGES + e, i64);
        atomicAdd(&h[c >> BSH], 1);
    }
    __syncthreads();
    for (int i = tid; i < NBUCK; i += 256) hist[(long)blockIdx.x * NBUCK + i] = h[i];
}

__global__ __launch_bounds__(256) void k2a(const int* __restrict__ hist,
                                           int* __restrict__ pexcl,
                                           int* __restrict__ total) {
    __shared__ int tmp[256];
    int b = blockIdx.x, t = threadIdx.x;
    int v = hist[(long)t * NBUCK + b];
    tmp[t] = v;
    __syncthreads();
    for (int off = 1; off < 256; off <<= 1) {
        int u = (t >= off) ? tmp[t - off] : 0;
        __syncthreads();
        tmp[t] += u;
        __syncthreads();
    }
    pexcl[(long)t * NBUCK + b] = tmp[t] - v;
    if (t == 255) total[b] = tmp[255];
}

__global__ __launch_bounds__(256) void k2b(const int* __restrict__ total,
                                           int* __restrict__ bucket_base) {
    __shared__ int tmp[256];
    int t = threadIdx.x;
    int v = (t < NBUCK) ? total[t] : 0;
    tmp[t] = v;
    __syncthreads();
    for (int off = 1; off < 256; off <<= 1) {
        int u = (t >= off) ? tmp[t - off] : 0;
        __syncthreads();
        tmp[t] += u;
        __syncthreads();
    }
    if (t < NBUCK) bucket_base[t] = tmp[t] - v;
    if (t == 255) bucket_base[NBUCK] = tmp[255];
}

__global__ __launch_bounds__(256) void k3_scatter(const int* __restrict__ ei,
                                                  const int* __restrict__ flags,
                                                  const int* __restrict__ pexcl,
                                                  const int* __restrict__ bucket_base,
                                                  uint* __restrict__ bstore) {
    __shared__ int pos[NBUCK];
    int tid = threadIdx.x;
    for (int i = tid; i < NBUCK; i += 256)
        pos[i] = bucket_base[i] + pexcl[(long)blockIdx.x * NBUCK + i];
    __syncthreads();
    int i64 = flags[1];
    for (int e = blockIdx.x * 256 + tid; e < N_EDGES; e += NB1 * 256) {
        int r = geti(ei, e, i64);
        int c = geti(ei, (long)N_EDGES + e, i64);
        int p = atomicAdd(&pos[c >> BSH], 1);
        bstore[p] = ((uint)r << BSH) | (uint)(c & 511);
    }
}

__global__ __launch_bounds__(256) void k4_csr(const uint* __restrict__ bstore,
                                              const int* __restrict__ bucket_base,
                                              int* __restrict__ deg,
                                              float* __restrict__ dinv,
                                              int* __restrict__ row_end,
                                              int* __restrict__ csr_src) {
    __shared__ int cnt[512];
    __shared__ int exc[512];
    __shared__ int tmp[256];
    int b = blockIdx.x, t = threadIdx.x;
    cnt[t] = 0; cnt[t + 256] = 0;
    __syncthreads();
    int bb = bucket_base[b];
    int m = bucket_base[b + 1] - bb;
    const uint* bs = bstore + bb;
    for (int i = t; i < m; i += 256) atomicAdd(&cnt[bs[i] & 511], 1);
    __syncthreads();
    int c0 = cnt[2 * t], c1 = cnt[2 * t + 1];
    tmp[t] = c0 + c1;
    __syncthreads();
    for (int off = 1; off < 256; off <<= 1) {
        int u = (t >= off) ? tmp[t - off] : 0;
        __syncthreads();
        tmp[t] += u;
        __syncthreads();
    }
    int ep = tmp[t] - (c0 + c1);
    exc[2 * t] = ep;
    exc[2 * t + 1] = ep + c0;
    int n0 = (b << BSH) + 2 * t;
    if (n0 < N_NODES) {
        deg[n0] = c0;
        dinv[n0] = rsqrtf((float)c0 + 1.0f);
        row_end[n0] = bb + ep + c0;
    }
    if (n0 + 1 < N_NODES) {
        deg[n0 + 1] = c1;
        dinv[n0 + 1] = rsqrtf((float)c1 + 1.0f);
        row_end[n0 + 1] = bb + ep + c0 + c1;
    }
    __syncthreads();
    for (int i = t; i < m; i += 256) {
        uint p = bs[i];
        int pos = atomicAdd(&exc[p & 511], 1);
        csr_src[bb + pos] = (int)(p >> BSH);
    }
}

// ---------------- MFMA input linear (pre / emb) ----------------
template <int K, int KA>
__global__ __launch_bounds__(256) void k_mm_in(const void* __restrict__ A0,
                                               const void* __restrict__ W,
                                               const void* __restrict__ Bv,
                                               const int* __restrict__ flags,
                                               bf16* __restrict__ outp) {
    __shared__ short wT[64 * (K + 8)];
    __shared__ float bl[64];
    const int isf32 = flags[0];
    const int tid = threadIdx.x;
    for (int i = tid; i < 64 * K; i += 256) {
        int k = i >> 6, f = i & 63;
        float v = (k < KA) ? ldf(W, i, isf32) : 0.f;
        wT[f * (K + 8) + k] = f2bs(v);
    }
    if (tid < 64) bl[tid] = ldf(Bv, tid, isf32);
    __syncthreads();

    const int lane = tid & 63, wv = tid >> 6;
    const int m = lane & 15, quad = lane >> 4;

    short8 bfr[4][K / 32];
    #pragma unroll
    for (int cb = 0; cb < 4; cb++)
        #pragma unroll
        for (int ks = 0; ks < K / 32; ks++)
            bfr[cb][ks] = *(const short8*)&wT[(cb * 16 + m) * (K + 8) + ks * 32 + quad * 8];

    for (int t = blockIdx.x * 4 + wv; t < NTILES; t += gridDim.x * 4) {
        const int n0 = t * 16;
        short8 af[K / 32];
        if (isf32) {
            const float* Af = (const float*)A0 + (long)(n0 + m) * KA;
            #pragma unroll
            for (int ks = 0; ks < K / 32; ks++) {
                short8 a;
                #pragma unroll
                for (int j = 0; j < 8; j++) {
                    int k = ks * 32 + quad * 8 + j;
                    float v = (KA % 32 == 0 || k < KA) ? Af[k] : 0.f;
                    a[j] = f2bs(v);
                }
                af[ks] = a;
            }
        } else {
            const bf16* Ab = (const bf16*)A0 + (long)(n0 + m) * KA;
            #pragma unroll
            for (int ks = 0; ks < K / 32; ks++) {
                if constexpr (KA % 32 == 0) {
                    af[ks] = *(const short8*)&Ab[ks * 32 + quad * 8];
                } else {
                    short8 a;
                    #pragma unroll
                    for (int j = 0; j < 8; j++) {
                        int k = ks * 32 + quad * 8 + j;
                        float v = (k < KA) ? b2f(Ab[k]) : 0.f;
                        a[j] = f2bs(v);
                    }
                    af[ks] = a;
                }
            }
        }
        float4v c[4];
        #pragma unroll
        for (int cb = 0; cb < 4; cb++) { c[cb][0]=0.f; c[cb][1]=0.f; c[cb][2]=0.f; c[cb][3]=0.f; }
        #pragma unroll
        for (int ks = 0; ks < K / 32; ks++)
            #pragma unroll
            for (int cb = 0; cb < 4; cb++)
                c[cb] = __builtin_amdgcn_mfma_f32_16x16x32_bf16(af[ks], bfr[cb][ks], c[cb], 0, 0, 0);
        #pragma unroll
        for (int cb = 0; cb < 4; cb++) {
            int feat = cb * 16 + m;
            #pragma unroll
            for (int r = 0; r < 4; r++) {
                int n = n0 + quad * 4 + r;
                outp[(long)n * 64 + feat] = f2b(c[cb][r] + bl[feat]);
            }
        }
    }
}

// ---------------- mmA: zsw[n][0:64]=[x,s]@W1 ; zsw[n][64:128]=dinv*(s@Wg) ----------------
__global__ __launch_bounds__(256) void k_mmA(const bf16* __restrict__ x,
                                             const bf16* __restrict__ s,
                                             const void* __restrict__ W1,
                                             const void* __restrict__ Wg,
                                             const float* __restrict__ dinv,
                                             const int* __restrict__ flags,
                                             long w1_off, long wg_off,
                                             bf16* __restrict__ zsw) {
    __shared__ short wT1[64 * 136];
    __shared__ short wTg[64 * 72];
    const int isf32 = flags[0];
    const int tid = threadIdx.x;
    for (int i = tid; i < 64 * 128; i += 256) {
        int k = i >> 6, f = i & 63;
        wT1[f * 136 + k] = f2bs(ldf(W1, w1_off + i, isf32));
    }
    for (int i = tid; i < 64 * 64; i += 256) {
        int k = i >> 6, f = i & 63;
        wTg[f * 72 + k] = f2bs(ldf(Wg, wg_off + i, isf32));
    }
    __syncthreads();

    const int lane = tid & 63, wv = tid >> 6;
    const int m = lane & 15, quad = lane >> 4;

    short8 w1f[4][4], wgf[4][2];
    #pragma unroll
    for (int cb = 0; cb < 4; cb++) {
        #pragma unroll
        for (int ks = 0; ks < 4; ks++)
            w1f[cb][ks] = *(const short8*)&wT1[(cb * 16 + m) * 136 + ks * 32 + quad * 8];
        #pragma unroll
        for (int ks = 0; ks < 2; ks++)
            wgf[cb][ks] = *(const short8*)&wTg[(cb * 16 + m) * 72 + ks * 32 + quad * 8];
    }

    for (int t = blockIdx.x * 4 + wv; t < NTILES; t += gridDim.x * 4) {
        const int n0 = t * 16;
        short8 a[4];
        a[0] = *(const short8*)&x[(long)(n0 + m) * 64 + quad * 8];
        a[1] = *(const short8*)&x[(long)(n0 + m) * 64 + 32 + quad * 8];
        a[2] = *(const short8*)&s[(long)(n0 + m) * 64 + quad * 8];
        a[3] = *(const short8*)&s[(long)(n0 + m) * 64 + 32 + quad * 8];
        float4v cz[4], cd[4];
        #pragma unroll
        for (int cb = 0; cb < 4; cb++) {
            cz[cb][0]=0.f; cz[cb][1]=0.f; cz[cb][2]=0.f; cz[cb][3]=0.f;
            cd[cb][0]=0.f; cd[cb][1]=0.f; cd[cb][2]=0.f; cd[cb][3]=0.f;
        }
        #pragma unroll
        for (int ks = 0; ks < 4; ks++)
            #pragma unroll
            for (int cb = 0; cb < 4; cb++)
                cz[cb] = __builtin_amdgcn_mfma_f32_16x16x32_bf16(a[ks], w1f[cb][ks], cz[cb], 0, 0, 0);
        #pragma unroll
        for (int ks = 0; ks < 2; ks++)
            #pragma unroll
            for (int cb = 0; cb < 4; cb++)
                cd[cb] = __builtin_amdgcn_mfma_f32_16x16x32_bf16(a[2 + ks], wgf[cb][ks], cd[cb], 0, 0, 0);
        #pragma unroll
        for (int cb = 0; cb < 4; cb++) {
            int feat = cb * 16 + m;
            #pragma unroll
            for (int r = 0; r < 4; r++) {
                int n = n0 + quad * 4 + r;
                zsw[(long)n * 128 + feat] = f2b(cz[cb][r]);
                zsw[(long)n * 128 + 64 + feat] = f2b(cd[cb][r] * dinv[n]);
            }
        }
    }
}

// ---------------- mmB: x'=relu(hB@W2+b2) [wave-private LDS]; zsw=[x',s]@W1n | dinv*(s@Wgn) ----------------
__global__ __launch_bounds__(256) void k_mmB(const bf16* __restrict__ hB,
                                             const bf16* __restrict__ s,
                                             const void* __restrict__ W2,
                                             const void* __restrict__ B2,
                                             const void* __restrict__ W1n,
                                             const void* __restrict__ Wgn,
                                             const float* __restrict__ dinv,
                                             const int* __restrict__ flags,
                                             long w2_off, long b2_off, long w1n_off, long wgn_off,
                                             bf16* __restrict__ zsw) {
    __shared__ short wT2[64 * 72];
    __shared__ short wT1[64 * 136];
    __shared__ short wTg[64 * 72];
    __shared__ float bl2[64];
    __shared__ short xbuf[4][16 * 72];
    const int isf32 = flags[0];
    const int tid = threadIdx.x;
    for (int i = tid; i < 64 * 64; i += 256) {
        int k = i >> 6, f = i & 63;
        wT2[f * 72 + k] = f2bs(ldf(W2, w2_off + i, isf32));
        wTg[f * 72 + k] = f2bs(ldf(Wgn, wgn_off + i, isf32));
    }
    for (int i = tid; i < 64 * 128; i += 256) {
        int k = i >> 6, f = i & 63;
        wT1[f * 136 + k] = f2bs(ldf(W1n, w1n_off + i, isf32));
    }
    if (tid < 64) bl2[tid] = ldf(B2, b2_off + tid, isf32);
    __syncthreads();

    const int lane = tid & 63, wv = tid >> 6;
    const int m = lane & 15, quad = lane >> 4;

    short8 w2f[4][2], w1f[4][4];
    #pragma unroll
    for (int cb = 0; cb < 4; cb++) {
        #pragma unroll
        for (int ks = 0; ks < 2; ks++)
            w2f[cb][ks] = *(const short8*)&wT2[(cb * 16 + m) * 72 + ks * 32 + quad * 8];
        #pragma unroll
        for (int ks = 0; ks < 4; ks++)
            w1f[cb][ks] = *(const short8*)&wT1[(cb * 16 + m) * 136 + ks * 32 + quad * 8];
    }

    // xbuf[wv] is wave-private: no block barrier needed in the tile loop,
    // only a compiler scheduling fence (wave DS ops execute in order).
    for (int t = blockIdx.x * 4 + wv; t < NTILES; t += gridDim.x * 4) {
        const int n0 = t * 16;
        {
            short8 ah[2];
            ah[0] = *(const short8*)&hB[(long)(n0 + m) * 64 + quad * 8];
            ah[1] = *(const short8*)&hB[(long)(n0 + m) * 64 + 32 + quad * 8];
            float4v cx[4];
            #pragma unroll
            for (int cb = 0; cb < 4; cb++) { cx[cb][0]=0.f; cx[cb][1]=0.f; cx[cb][2]=0.f; cx[cb][3]=0.f; }
            #pragma unroll
            for (int ks = 0; ks < 2; ks++)
                #pragma unroll
                for (int cb = 0; cb < 4; cb++)
                    cx[cb] = __builtin_amdgcn_mfma_f32_16x16x32_bf16(ah[ks], w2f[cb][ks], cx[cb], 0, 0, 0);
            #pragma unroll
            for (int cb = 0; cb < 4; cb++) {
                int feat = cb * 16 + m;
                float bb = bl2[feat];
                #pragma unroll
                for (int r = 0; r < 4; r++)
                    xbuf[wv][(quad * 4 + r) * 72 + feat] = f2bs(fmaxf(cx[cb][r] + bb, 0.f));
            }
        }
        __builtin_amdgcn_wave_barrier();
        {
            short8 a[4];
            a[0] = *(const short8*)&xbuf[wv][m * 72 + quad * 8];
            a[1] = *(const short8*)&xbuf[wv][m * 72 + 32 + quad * 8];
            a[2] = *(const short8*)&s[(long)(n0 + m) * 64 + quad * 8];
            a[3] = *(const short8*)&s[(long)(n0 + m) * 64 + 32 + quad * 8];
            float4v cz[4], cd[4];
            #pragma unroll
            for (int cb = 0; cb < 4; cb++) {
                cz[cb][0]=0.f; cz[cb][1]=0.f; cz[cb][2]=0.f; cz[cb][3]=0.f;
                cd[cb][0]=0.f; cd[cb][1]=0.f; cd[cb][2]=0.f; cd[cb][3]=0.f;
            }
            #pragma unroll
            for (int ks = 0; ks < 4; ks++)
                #pragma unroll
                for (int cb = 0; cb < 4; cb++)
                    cz[cb] = __builtin_amdgcn_mfma_f32_16x16x32_bf16(a[ks], w1f[cb][ks], cz[cb], 0, 0, 0);
            #pragma unroll
            for (int ks = 0; ks < 2; ks++)
                #pragma unroll
                for (int cb = 0; cb < 4; cb++) {
                    short8 bg = *(const short8*)&wTg[(cb * 16 + m) * 72 + ks * 32 + quad * 8];
                    cd[cb] = __builtin_amdgcn_mfma_f32_16x16x32_bf16(a[2 + ks], bg, cd[cb], 0, 0, 0);
                }
            #pragma unroll
            for (int cb = 0; cb < 4; cb++) {
                int feat = cb * 16 + m;
                #pragma unroll
                for (int r = 0; r < 4; r++) {
                    int n = n0 + quad * 4 + r;
                    zsw[(long)n * 128 + feat] = f2b(cz[cb][r]);
                    zsw[(long)n * 128 + 64 + feat] = f2b(cd[cb][r] * dinv[n]);
                }
            }
        }
        __builtin_amdgcn_wave_barrier();
    }
}

// ---------------- mmC: x'=relu(hB@W2+b2); wout=[x',s]@Whp+bw; pool into xp ----------------
__global__ __launch_bounds__(256) void k_mmC(const bf16* __restrict__ hB,
                                             const bf16* __restrict__ s,
                                             const void* __restrict__ W2,
                                             const void* __restrict__ B2,
                                             const void* __restrict__ Ww,
                                             const void* __restrict__ Bw,
                                             const int* __restrict__ batch,
                                             const int* __restrict__ flags,
                                             long w2_off, long b2_off,
                                             float* __restrict__ xp) {
    __shared__ short wT2[64 * 72];
    __shared__ short wTw[64 * 136];
    __shared__ float bl2[64], blw[64];
    __shared__ short xbuf[4][16 * 72];
    const int isf32 = flags[0];
    const int i64 = flags[1];
    const int tid = threadIdx.x;
    for (int i = tid; i < 64 * 64; i += 256) {
        int k = i >> 6, f = i & 63;
        wT2[f * 72 + k] = f2bs(ldf(W2, w2_off + i, isf32));
    }
    for (int i = tid; i < 64 * 128; i += 256) {
        int k = i >> 6, f = i & 63;
        wTw[f * 136 + k] = f2bs(ldf(Ww, i, isf32));
    }
    if (tid < 64) { bl2[tid] = ldf(B2, b2_off + tid, isf32); blw[tid] = ldf(Bw, tid, isf32); }
    __syncthreads();

    const int lane = tid & 63, wv = tid >> 6;
    const int m = lane & 15, quad = lane >> 4;

    short8 w2f[4][2], wwf[4][4];
    #pragma unroll
    for (int cb = 0; cb < 4; cb++) {
        #pragma unroll
        for (int ks = 0; ks < 2; ks++)
            w2f[cb][ks] = *(const short8*)&wT2[(cb * 16 + m) * 72 + ks * 32 + quad * 8];
        #pragma unroll
        for (int ks = 0; ks < 4; ks++)
            wwf[cb][ks] = *(const short8*)&wTw[(cb * 16 + m) * 136 + ks * 32 + quad * 8];
    }

    for (int t = blockIdx.x * 4 + wv; t < NTILES; t += gridDim.x * 4) {
        const int n0 = t * 16;
        {
            short8 ah[2];
            ah[0] = *(const short8*)&hB[(long)(n0 + m) * 64 + quad * 8];
            ah[1] = *(const short8*)&hB[(long)(n0 + m) * 64 + 32 + quad * 8];
            float4v cx[4];
            #pragma unroll
            for (int cb = 0; cb < 4; cb++) { cx[cb][0]=0.f; cx[cb][1]=0.f; cx[cb][2]=0.f; cx[cb][3]=0.f; }
            #pragma unroll
            for (int ks = 0; ks < 2; ks++)
                #pragma unroll
                for (int cb = 0; cb < 4; cb++)
                    cx[cb] = __builtin_amdgcn_mfma_f32_16x16x32_bf16(ah[ks], w2f[cb][ks], cx[cb], 0, 0, 0);
            #pragma unroll
            for (int cb = 0; cb < 4; cb++) {
                int feat = cb * 16 + m;
                float bb = bl2[feat];
                #pragma unroll
                for (int r = 0; r < 4; r++)
                    xbuf[wv][(quad * 4 + r) * 72 + feat] = f2bs(fmaxf(cx[cb][r] + bb, 0.f));
            }
        }
        __builtin_amdgcn_wave_barrier();
        {
            short8 a[4];
            a[0] = *(const short8*)&xbuf[wv][m * 72 + quad * 8];
            a[1] = *(const short8*)&xbuf[wv][m * 72 + 32 + quad * 8];
            a[2] = *(const short8*)&s[(long)(n0 + m) * 64 + quad * 8];
            a[3] = *(const short8*)&s[(long)(n0 + m) * 64 + 32 + quad * 8];
            float4v cz[4];
            #pragma unroll
            for (int cb = 0; cb < 4; cb++) { cz[cb][0]=0.f; cz[cb][1]=0.f; cz[cb][2]=0.f; cz[cb][3]=0.f; }
            #pragma unroll
            for (int ks = 0; ks < 4; ks++)
                #pragma unroll
                for (int cb = 0; cb < 4; cb++)
                    cz[cb] = __builtin_amdgcn_mfma_f32_16x16x32_bf16(a[ks], wwf[cb][ks], cz[cb], 0, 0, 0);
            int g[4];
            #pragma unroll
            for (int r = 0; r < 4; r++) g[r] = geti(batch, n0 + quad * 4 + r, i64);
            #pragma unroll
            for (int cb = 0; cb < 4; cb++) {
                int feat = cb * 16 + m;
                float bw = blw[feat];
                int gp = g[0];
                float acc = cz[cb][0] + bw;
                #pragma unroll
                for (int r = 1; r < 4; r++) {
                    if (g[r] == gp) acc += cz[cb][r] + bw;
                    else { atomicAdd(&xp[(long)gp * 64 + feat], acc); gp = g[r]; acc = cz[cb][r] + bw; }
                }
                atomicAdd(&xp[(long)gp * 64 + feat], acc);
            }
        }
        __builtin_amdgcn_wave_barrier();
    }
}

// ---------------- fused GIN+GCN gather, 4 rows per memory instruction ----------------
__global__ __launch_bounds__(256) void k_gather4(const uint* __restrict__ zsw,
                                                 const int* __restrict__ row_end,
                                                 const int* __restrict__ deg,
                                                 const int* __restrict__ csr_src,
                                                 const void* __restrict__ b1,
                                                 const void* __restrict__ bg,
                                                 const float* __restrict__ dinv,
                                                 const int* __restrict__ flags,
                                                 long b_off,
                                                 uint* __restrict__ hB,
                                                 uint* __restrict__ sOut) {
    int tid = threadIdx.x;
    int wv = tid >> 6, lane = tid & 63;
    int grp = lane >> 4, sub = lane & 15;
    int n = blockIdx.x * 4 + wv;
    if (n >= N_NODES) return;
    int end = row_end[n], dg = deg[n];
    int beg = end - dg;
    int R = dg + 1;                         // rows incl. self (idx 0)
    const uint4* zp = (const uint4*)zsw;    // row n = uint4 index n*16 + sub
    float a[8];
    #pragma unroll
    for (int j = 0; j < 8; j++) a[j] = 0.f;
    for (int i = 0; i < R; i += 8) {
        int iA = i + grp, iB = i + 4 + grp;
        uint4 uA = {0, 0, 0, 0}, uB = {0, 0, 0, 0};
        if (iA < R) {
            int sA = (iA == 0) ? n : csr_src[beg + iA - 1];
            uA = zp[(long)sA * 16 + sub];
        }
        if (iB < R) {
            int sB = csr_src[beg + iB - 1];
            uB = zp[(long)sB * 16 + sub];
        }
        a[0] += bflo(uA.x) + bflo(uB.x);
        a[1] += bfhi(uA.x) + bfhi(uB.x);
        a[2] += bflo(uA.y) + bflo(uB.y);
        a[3] += bfhi(uA.y) + bfhi(uB.y);
        a[4] += bflo(uA.z) + bflo(uB.z);
        a[5] += bfhi(uA.z) + bfhi(uB.z);
        a[6] += bflo(uA.w) + bflo(uB.w);
        a[7] += bfhi(uA.w) + bfhi(uB.w);
    }
    #pragma unroll
    for (int j = 0; j < 8; j++) {
        a[j] += __shfl_xor(a[j], 16);
        a[j] += __shfl_xor(a[j], 32);
    }
    int q = 4 * sub + grp;
    float v0 = a[2 * grp], v1 = a[2 * grp + 1];
    int isf32 = flags[0];
    if (q < 32) {
        float c0 = ldf(b1, b_off + 2 * q, isf32);
        float c1 = ldf(b1, b_off + 2 * q + 1, isf32);
        hB[(long)n * 32 + q] = packbf(fmaxf(v0 + c0, 0.f), fmaxf(v1 + c1, 0.f));
    } else {
        int qq = q - 32;
        float c0 = ldf(bg, b_off + 2 * qq, isf32);
        float c1 = ldf(bg, b_off + 2 * qq + 1, isf32);
        float dn = dinv[n];
        sOut[(long)n * 32 + qq] = packbf(tanhf(dn * v0 + c0), tanhf(dn * v1 + c1));
    }
}

// ---------------- final: post + readout + log_softmax ----------------
__global__ __launch_bounds__(64) void k_final(const float* __restrict__ xp,
                                              const void* __restrict__ post_w,
                                              const void* __restrict__ post_b,
                                              const void* __restrict__ ro_w,
                                              const void* __restrict__ ro_b,
                                              const int* __restrict__ flags,
                                              void* __restrict__ out) {
    __shared__ float h2[64];
    __shared__ float lg[16];
    int isf32 = flags[0];
    int g = blockIdx.x;
    int f = threadIdx.x;
    float xr = xp[(long)g * 64 + f];
    float acc = ldf(post_b, f, isf32);
    #pragma unroll
    for (int j = 0; j < 64; j++) acc += __shfl(xr, j) * ldf(post_w, j * 64 + f, isf32);
    float v = fmaxf(acc, 0.f);
    h2[f] = v;
    long oxp = (long)g * 64 + f;
    if (isf32) ((float*)out)[oxp] = v; else ((bf16*)out)[oxp] = f2b(v);
    __syncthreads();
    if (f < 16) {
        float a = ldf(ro_b, f, isf32);
        for (int j = 0; j < 64; j++) a += h2[j] * ldf(ro_w, j * 16 + f, isf32);
        lg[f] = a;
    }
    __syncthreads();
    if (f < 16) {
        float m = -1e30f;
        for (int j = 0; j < 16; j++) m = fmaxf(m, lg[j]);
        float sum = 0.f;
        for (int j = 0; j < 16; j++) sum += expf(lg[j] - m);
        long oy = (long)N_GRAPHS * 64 + (long)g * 16 + f;
        float yv = lg[f] - m - logf(sum);
        if (isf32) ((float*)out)[oy] = yv; else ((bf16*)out)[oy] = f2b(yv);
    }
}

extern "C" void kernel_launch(void* const* d_in, const int* in_sizes, int n_in,
                              void* d_out, int out_size, void* d_ws, size_t ws_size,
                              hipStream_t stream) {
    const void* x_in  = d_in[0];
    const void* s_in  = d_in[1];
    const int*  ei    = (const int*)d_in[2];
    const int*  batch = (const int*)d_in[3];
    const void* pre_w = d_in[4];
    const void* pre_b = d_in[5];
    const void* emb_w = d_in[6];
    const void* emb_b = d_in[7];
    const void* gin_w1 = d_in[8];
    const void* gin_b1 = d_in[9];
    const void* gin_w2 = d_in[10];
    const void* gin_b2 = d_in[11];
    const void* gcn_w  = d_in[12];
    const void* gcn_b  = d_in[13];
    const void* whp_w  = d_in[14];
    const void* whp_b  = d_in[15];
    const void* post_w = d_in[16];
    const void* post_b = d_in[17];
    const void* ro_w   = d_in[18];
    const void* ro_b   = d_in[19];

    int* flags   = (int*)d_ws;
    int* deg     = flags + 64;
    int* row_end = deg + N_NODES;
    int* hist    = row_end + N_NODES;
    int* pexcl   = hist + NB1 * NBUCK;
    int* total   = pexcl + NB1 * NBUCK;
    int* bbase   = total + NBUCK;
    uint* bstore = (uint*)(bbase + NBUCK + 4);
    int* csr_src = (int*)(bstore + N_EDGES);
    float* dinv  = (float*)(csr_src + N_EDGES);
    bf16* x0     = (bf16*)(dinv + N_NODES);
    bf16* sA     = x0 + (long)N_NODES * 64;
    bf16* hB     = sA + (long)N_NODES * 64;
    uint* zsw    = (uint*)(hB + (long)N_NODES * 64);
    float* xp    = (float*)(zsw + (long)N_NODES * 64);

    const int MMB_A = 1024;   // mm_in / mmA: ~4-6 blocks/CU for latency hiding
    const int MMB_B = 768;    // mmB / mmC: 45KB LDS -> 3 blocks/CU
    const int GGB = (N_NODES + 3) / 4;       // 25000

    k_detect<<<1, 64, 0, stream>>>(x_in, ei, flags);

    // CSR + deg + dinv + row_end: two-pass radix partition
    k1_hist<<<NB1, 256, 0, stream>>>(ei, flags, hist);
    k2a<<<NBUCK, 256, 0, stream>>>(hist, pexcl, total);
    k2b<<<1, 256, 0, stream>>>(total, bbase);
    k3_scatter<<<NB1, 256, 0, stream>>>(ei, flags, pexcl, bbase, bstore);
    k4_csr<<<NBUCK, 256, 0, stream>>>(bstore, bbase, deg, dinv, row_end, csr_src);

    const long W1 = 128 * 64, W2 = 64 * 64, WG = 64 * 64, B = 64;

    // pre / embedding -> bf16 activations
    k_mm_in<128, 128><<<MMB_A, 256, 0, stream>>>(x_in, pre_w, pre_b, flags, x0);
    k_mm_in<32, 16><<<MMB_A, 256, 0, stream>>>(s_in, emb_w, emb_b, flags, sA);

    // ---- layer 0 ----
    k_mmA<<<MMB_A, 256, 0, stream>>>(x0, sA, gin_w1, gcn_w, dinv, flags, 0L, 0L, (bf16*)zsw);
    k_gather4<<<GGB, 256, 0, stream>>>(zsw, row_end, deg, csr_src, gin_b1, gcn_b, dinv, flags, 0L, (uint*)hB, (uint*)sA);

    // ---- layer 0 tail fused with layer 1 head ----
    k_mmB<<<MMB_B, 256, 0, stream>>>(hB, sA, gin_w2, gin_b2, gin_w1, gcn_w, dinv, flags,
                                     0L, 0L, W1, WG, (bf16*)zsw);
    k_gather4<<<GGB, 256, 0, stream>>>(zsw, row_end, deg, csr_src, gin_b1, gcn_b, dinv, flags, B, (uint*)hB, (uint*)sA);

    // ---- layer 1 tail + whp + pool ----
    hipMemsetAsync(xp, 0, (size_t)N_GRAPHS * 64 * sizeof(float), stream);
    k_mmC<<<MMB_B, 256, 0, stream>>>(hB, sA, gin_w2, gin_b2, whp_w, whp_b, batch, flags,
                                     W2, B, xp);

    k_final<<<N_GRAPHS, 64, 0, stream>>>(xp, post_w, post_b, ro_w, ro_b, flags, d_out);
}

// Round 12
// 521.280 us; speedup vs baseline: 1.0721x; 1.0721x over previous
//
#include <hip/hip_runtime.h>
#include <hip/hip_bf16.h>

#define N_NODES 100000
#define N_EDGES 1600000
#define N_GRAPHS 512
#define NTILES (N_NODES / 16)          // 6250, exact
#define BSH 9                          // 512 nodes per bucket
#define NBUCK ((N_NODES + 511) >> BSH) // 196
#define NB1 256                        // blocks for hist/scatter passes

typedef __hip_bfloat16 bf16;
typedef unsigned int uint;
typedef unsigned short ushort;
typedef __attribute__((ext_vector_type(8))) short short8;
typedef __attribute__((ext_vector_type(4))) float float4v;

__device__ __forceinline__ float b2f(bf16 v) { return __bfloat162float(v); }
__device__ __forceinline__ bf16 f2b(float v) { return __float2bfloat16(v); }
__device__ __forceinline__ short f2bs(float v) { bf16 h = f2b(v); return *(short*)&h; }

__device__ __forceinline__ float ldf(const void* p, long i, int isf32) {
    return isf32 ? ((const float*)p)[i] : b2f(((const bf16*)p)[i]);
}
__device__ __forceinline__ int geti(const int* p, long i, int is64) {
    return is64 ? p[2 * i] : p[i];
}
__device__ __forceinline__ float bflo(uint u) { return __uint_as_float(u << 16); }
__device__ __forceinline__ float bfhi(uint u) { return __uint_as_float(u & 0xffff0000u); }
__device__ __forceinline__ uint packbf(float x, float y) {
    bf16 a = f2b(x), b = f2b(y);
    ushort ua = *(ushort*)&a, ub = *(ushort*)&b;
    return (uint)ua | ((uint)ub << 16);
}

// ---------------- dtype detection ----------------
__global__ void k_detect(const void* __restrict__ x, const int* __restrict__ ei,
                         int* __restrict__ flags) {
    if (threadIdx.x != 0 || blockIdx.x != 0) return;
    const ushort* xu = (const ushort*)x;
    int plaus = 0;
    for (int i = 0; i < 256; i++) {
        ushort u = xu[2 * i];
        int e = (u >> 7) & 0xFF;
        if (u == 0 || (e >= 116 && e <= 132)) plaus++;
    }
    flags[0] = (plaus < 128) ? 1 : 0;          // 1 => fp32 inputs
    int nz = 0;
    for (int i = 0; i < 128; i++) if (ei[2 * i + 1] != 0) nz++;
    flags[1] = (nz < 8) ? 1 : 0;               // 1 => int64 indices
}

// ---------------- CSR build: deterministic 2-pass radix partition ----------------
__global__ __launch_bounds__(256) void k1_hist(const int* __restrict__ ei,
                                               const int* __restrict__ flags,
                                               int* __restrict__ hist) {
    __shared__ int h[NBUCK];
    int tid = threadIdx.x;
    for (int i = tid; i < NBUCK; i += 256) h[i] = 0;
    __syncthreads();
    int i64 = flags[1];
    for (int e = blockIdx.x * 256 + tid; e < N_EDGES; e += NB1 * 256) {
        int c = geti(ei, (long)N_EDGES + e, i64);
        atomicAdd(&h[c >> BSH], 1);
    }
    __syncthreads();
    for (int i = tid; i < NBUCK; i += 256) hist[(long)blockIdx.x * NBUCK + i] = h[i];
}

__global__ __launch_bounds__(256) void k2a(const int* __restrict__ hist,
                                           int* __restrict__ pexcl,
                                           int* __restrict__ total) {
    __shared__ int tmp[256];
    int b = blockIdx.x, t = threadIdx.x;
    int v = hist[(long)t * NBUCK + b];
    tmp[t] = v;
    __syncthreads();
    for (int off = 1; off < 256; off <<= 1) {
        int u = (t >= off) ? tmp[t - off] : 0;
        __syncthreads();
        tmp[t] += u;
        __syncthreads();
    }
    pexcl[(long)t * NBUCK + b] = tmp[t] - v;
    if (t == 255) total[b] = tmp[255];
}

__global__ __launch_bounds__(256) void k2b(const int* __restrict__ total,
                                           int* __restrict__ bucket_base) {
    __shared__ int tmp[256];
    int t = threadIdx.x;
    int v = (t < NBUCK) ? total[t] : 0;
    tmp[t] = v;
    __syncthreads();
    for (int off = 1; off < 256; off <<= 1) {
        int u = (t >= off) ? tmp[t - off] : 0;
        __syncthreads();
        tmp[t] += u;
        __syncthreads();
    }
    if (t < NBUCK) bucket_base[t] = tmp[t] - v;
    if (t == 255) bucket_base[NBUCK] = tmp[255];
}

__global__ __launch_bounds__(256) void k3_scatter(const int* __restrict__ ei,
                                                  const int* __restrict__ flags,
                                                  const int* __restrict__ pexcl,
                                                  const int* __restrict__ bucket_base,
                                                  uint* __restrict__ bstore) {
    __shared__ int pos[NBUCK];
    int tid = threadIdx.x;
    for (int i = tid; i < NBUCK; i += 256)
        pos[i] = bucket_base[i] + pexcl[(long)blockIdx.x * NBUCK + i];
    __syncthreads();
    int i64 = flags[1];
    for (int e = blockIdx.x * 256 + tid; e < N_EDGES; e += NB1 * 256) {
        int r = geti(ei, e, i64);
        int c = geti(ei, (long)N_EDGES + e, i64);
        int p = atomicAdd(&pos[c >> BSH], 1);
        bstore[p] = ((uint)r << BSH) | (uint)(c & 511);
    }
}

__global__ __launch_bounds__(256) void k4_csr(const uint* __restrict__ bstore,
                                              const int* __restrict__ bucket_base,
                                              int* __restrict__ deg,
                                              float* __restrict__ dinv,
                                              int* __restrict__ row_end,
                                              int* __restrict__ csr_src) {
    __shared__ int cnt[512];
    __shared__ int exc[512];
    __shared__ int tmp[256];
    int b = blockIdx.x, t = threadIdx.x;
    cnt[t] = 0; cnt[t + 256] = 0;
    __syncthreads();
    int bb = bucket_base[b];
    int m = bucket_base[b + 1] - bb;
    const uint* bs = bstore + bb;
    for (int i = t; i < m; i += 256) atomicAdd(&cnt[bs[i] & 511], 1);
    __syncthreads();
    int c0 = cnt[2 * t], c1 = cnt[2 * t + 1];
    tmp[t] = c0 + c1;
    __syncthreads();
    for (int off = 1; off < 256; off <<= 1) {
        int u = (t >= off) ? tmp[t - off] : 0;
        __syncthreads();
        tmp[t] += u;
        __syncthreads();
    }
    int ep = tmp[t] - (c0 + c1);
    exc[2 * t] = ep;
    exc[2 * t + 1] = ep + c0;
    int n0 = (b << BSH) + 2 * t;
    if (n0 < N_NODES) {
        deg[n0] = c0;
        dinv[n0] = rsqrtf((float)c0 + 1.0f);
        row_end[n0] = bb + ep + c0;
    }
    if (n0 + 1 < N_NODES) {
        deg[n0 + 1] = c1;
        dinv[n0 + 1] = rsqrtf((float)c1 + 1.0f);
        row_end[n0 + 1] = bb + ep + c0 + c1;
    }
    __syncthreads();
    for (int i = t; i < m; i += 256) {
        uint p = bs[i];
        int pos = atomicAdd(&exc[p & 511], 1);
        csr_src[bb + pos] = (int)(p >> BSH);
    }
}

// ---------------- MFMA input linear (pre / emb), wide LDS-transposed stores ----------------
template <int K, int KA>
__global__ __launch_bounds__(256) void k_mm_in(const void* __restrict__ A0,
                                               const void* __restrict__ W,
                                               const void* __restrict__ Bv,
                                               const int* __restrict__ flags,
                                               bf16* __restrict__ outp) {
    __shared__ short wT[64 * (K + 8)];
    __shared__ float bl[64];
    __shared__ short obuf[4][16 * 72];
    const int isf32 = flags[0];
    const int tid = threadIdx.x;
    for (int i = tid; i < 64 * K; i += 256) {
        int k = i >> 6, f = i & 63;
        float v = (k < KA) ? ldf(W, i, isf32) : 0.f;
        wT[f * (K + 8) + k] = f2bs(v);
    }
    if (tid < 64) bl[tid] = ldf(Bv, tid, isf32);
    __syncthreads();

    const int lane = tid & 63, wv = tid >> 6;
    const int m = lane & 15, quad = lane >> 4;

    short8 bfr[4][K / 32];
    #pragma unroll
    for (int cb = 0; cb < 4; cb++)
        #pragma unroll
        for (int ks = 0; ks < K / 32; ks++)
            bfr[cb][ks] = *(const short8*)&wT[(cb * 16 + m) * (K + 8) + ks * 32 + quad * 8];

    for (int t = blockIdx.x * 4 + wv; t < NTILES; t += gridDim.x * 4) {
        const int n0 = t * 16;
        short8 af[K / 32];
        if (isf32) {
            const float* Af = (const float*)A0 + (long)(n0 + m) * KA;
            #pragma unroll
            for (int ks = 0; ks < K / 32; ks++) {
                short8 a;
                #pragma unroll
                for (int j = 0; j < 8; j++) {
                    int k = ks * 32 + quad * 8 + j;
                    float v = (KA % 32 == 0 || k < KA) ? Af[k] : 0.f;
                    a[j] = f2bs(v);
                }
                af[ks] = a;
            }
        } else {
            const bf16* Ab = (const bf16*)A0 + (long)(n0 + m) * KA;
            #pragma unroll
            for (int ks = 0; ks < K / 32; ks++) {
                if constexpr (KA % 32 == 0) {
                    af[ks] = *(const short8*)&Ab[ks * 32 + quad * 8];
                } else {
                    short8 a;
                    #pragma unroll
                    for (int j = 0; j < 8; j++) {
                        int k = ks * 32 + quad * 8 + j;
                        float v = (k < KA) ? b2f(Ab[k]) : 0.f;
                        a[j] = f2bs(v);
                    }
                    af[ks] = a;
                }
            }
        }
        float4v c[4];
        #pragma unroll
        for (int cb = 0; cb < 4; cb++) { c[cb][0]=0.f; c[cb][1]=0.f; c[cb][2]=0.f; c[cb][3]=0.f; }
        #pragma unroll
        for (int ks = 0; ks < K / 32; ks++)
            #pragma unroll
            for (int cb = 0; cb < 4; cb++)
                c[cb] = __builtin_amdgcn_mfma_f32_16x16x32_bf16(af[ks], bfr[cb][ks], c[cb], 0, 0, 0);
        #pragma unroll
        for (int cb = 0; cb < 4; cb++) {
            int feat = cb * 16 + m;
            #pragma unroll
            for (int r = 0; r < 4; r++)
                obuf[wv][(quad * 4 + r) * 72 + feat] = f2bs(c[cb][r] + bl[feat]);
        }
        __builtin_amdgcn_wave_barrier();
        uint4* orow = (uint4*)(outp + (long)n0 * 64);
        #pragma unroll
        for (int it = 0; it < 2; it++) {
            int idx = it * 64 + lane;
            int row = idx >> 3, ch = idx & 7;
            orow[(long)row * 8 + ch] = *(const uint4*)&obuf[wv][row * 72 + ch * 8];
        }
        __builtin_amdgcn_wave_barrier();
    }
}

// ---------------- mmA: zsw row = [x,s]@W1 | dinv*(s@Wg), wide LDS-transposed stores ----------------
__global__ __launch_bounds__(256) void k_mmA(const bf16* __restrict__ x,
                                             const bf16* __restrict__ s,
                                             const void* __restrict__ W1,
                                             const void* __restrict__ Wg,
                                             const float* __restrict__ dinv,
                                             const int* __restrict__ flags,
                                             long w1_off, long wg_off,
                                             bf16* __restrict__ zsw) {
    __shared__ short wT1[64 * 136];
    __shared__ short wTg[64 * 72];
    __shared__ short obuf[4][16 * 136];
    const int isf32 = flags[0];
    const int tid = threadIdx.x;
    for (int i = tid; i < 64 * 128; i += 256) {
        int k = i >> 6, f = i & 63;
        wT1[f * 136 + k] = f2bs(ldf(W1, w1_off + i, isf32));
    }
    for (int i = tid; i < 64 * 64; i += 256) {
        int k = i >> 6, f = i & 63;
        wTg[f * 72 + k] = f2bs(ldf(Wg, wg_off + i, isf32));
    }
    __syncthreads();

    const int lane = tid & 63, wv = tid >> 6;
    const int m = lane & 15, quad = lane >> 4;

    short8 w1f[4][4], wgf[4][2];
    #pragma unroll
    for (int cb = 0; cb < 4; cb++) {
        #pragma unroll
        for (int ks = 0; ks < 4; ks++)
            w1f[cb][ks] = *(const short8*)&wT1[(cb * 16 + m) * 136 + ks * 32 + quad * 8];
        #pragma unroll
        for (int ks = 0; ks < 2; ks++)
            wgf[cb][ks] = *(const short8*)&wTg[(cb * 16 + m) * 72 + ks * 32 + quad * 8];
    }

    for (int t = blockIdx.x * 4 + wv; t < NTILES; t += gridDim.x * 4) {
        const int n0 = t * 16;
        short8 a[4];
        a[0] = *(const short8*)&x[(long)(n0 + m) * 64 + quad * 8];
        a[1] = *(const short8*)&x[(long)(n0 + m) * 64 + 32 + quad * 8];
        a[2] = *(const short8*)&s[(long)(n0 + m) * 64 + quad * 8];
        a[3] = *(const short8*)&s[(long)(n0 + m) * 64 + 32 + quad * 8];
        float4v cz[4], cd[4];
        #pragma unroll
        for (int cb = 0; cb < 4; cb++) {
            cz[cb][0]=0.f; cz[cb][1]=0.f; cz[cb][2]=0.f; cz[cb][3]=0.f;
            cd[cb][0]=0.f; cd[cb][1]=0.f; cd[cb][2]=0.f; cd[cb][3]=0.f;
        }
        #pragma unroll
        for (int ks = 0; ks < 4; ks++)
            #pragma unroll
            for (int cb = 0; cb < 4; cb++)
                cz[cb] = __builtin_amdgcn_mfma_f32_16x16x32_bf16(a[ks], w1f[cb][ks], cz[cb], 0, 0, 0);
        #pragma unroll
        for (int ks = 0; ks < 2; ks++)
            #pragma unroll
            for (int cb = 0; cb < 4; cb++)
                cd[cb] = __builtin_amdgcn_mfma_f32_16x16x32_bf16(a[2 + ks], wgf[cb][ks], cd[cb], 0, 0, 0);
        #pragma unroll
        for (int cb = 0; cb < 4; cb++) {
            int feat = cb * 16 + m;
            #pragma unroll
            for (int r = 0; r < 4; r++) {
                int row = quad * 4 + r;
                obuf[wv][row * 136 + feat] = f2bs(cz[cb][r]);
                obuf[wv][row * 136 + 64 + feat] = f2bs(cd[cb][r] * dinv[n0 + row]);
            }
        }
        __builtin_amdgcn_wave_barrier();
        uint4* orow = (uint4*)(zsw + (long)n0 * 128);
        #pragma unroll
        for (int it = 0; it < 4; it++) {
            int idx = it * 64 + lane;
            int row = idx >> 4, ch = idx & 15;
            orow[(long)row * 16 + ch] = *(const uint4*)&obuf[wv][row * 136 + ch * 8];
        }
        __builtin_amdgcn_wave_barrier();
    }
}

// ---------------- mmB: x'=relu(hB@W2+b2) [LDS]; zsw=[x',s]@W1n | dinv*(s@Wgn) ----------------
__global__ __launch_bounds__(256) void k_mmB(const bf16* __restrict__ hB,
                                             const bf16* __restrict__ s,
                                             const void* __restrict__ W2,
                                             const void* __restrict__ B2,
                                             const void* __restrict__ W1n,
                                             const void* __restrict__ Wgn,
                                             const float* __restrict__ dinv,
                                             const int* __restrict__ flags,
                                             long w2_off, long b2_off, long w1n_off, long wgn_off,
                                             bf16* __restrict__ zsw) {
    __shared__ short wT2[64 * 72];
    __shared__ short wT1[64 * 136];
    __shared__ short wTg[64 * 72];
    __shared__ float bl2[64];
    __shared__ short buf[4][16 * 136];   // x' handoff (cols 0..63), then z|swd output tile
    const int isf32 = flags[0];
    const int tid = threadIdx.x;
    for (int i = tid; i < 64 * 64; i += 256) {
        int k = i >> 6, f = i & 63;
        wT2[f * 72 + k] = f2bs(ldf(W2, w2_off + i, isf32));
        wTg[f * 72 + k] = f2bs(ldf(Wgn, wgn_off + i, isf32));
    }
    for (int i = tid; i < 64 * 128; i += 256) {
        int k = i >> 6, f = i & 63;
        wT1[f * 136 + k] = f2bs(ldf(W1n, w1n_off + i, isf32));
    }
    if (tid < 64) bl2[tid] = ldf(B2, b2_off + tid, isf32);
    __syncthreads();

    const int lane = tid & 63, wv = tid >> 6;
    const int m = lane & 15, quad = lane >> 4;

    short8 w2f[4][2], w1f[4][4];
    #pragma unroll
    for (int cb = 0; cb < 4; cb++) {
        #pragma unroll
        for (int ks = 0; ks < 2; ks++)
            w2f[cb][ks] = *(const short8*)&wT2[(cb * 16 + m) * 72 + ks * 32 + quad * 8];
        #pragma unroll
        for (int ks = 0; ks < 4; ks++)
            w1f[cb][ks] = *(const short8*)&wT1[(cb * 16 + m) * 136 + ks * 32 + quad * 8];
    }

    for (int t = blockIdx.x * 4 + wv; t < NTILES; t += gridDim.x * 4) {
        const int n0 = t * 16;
        // phase 1: x' = relu(hB@W2+b2) into buf cols 0..63
        {
            short8 ah[2];
            ah[0] = *(const short8*)&hB[(long)(n0 + m) * 64 + quad * 8];
            ah[1] = *(const short8*)&hB[(long)(n0 + m) * 64 + 32 + quad * 8];
            float4v cx[4];
            #pragma unroll
            for (int cb = 0; cb < 4; cb++) { cx[cb][0]=0.f; cx[cb][1]=0.f; cx[cb][2]=0.f; cx[cb][3]=0.f; }
            #pragma unroll
            for (int ks = 0; ks < 2; ks++)
                #pragma unroll
                for (int cb = 0; cb < 4; cb++)
                    cx[cb] = __builtin_amdgcn_mfma_f32_16x16x32_bf16(ah[ks], w2f[cb][ks], cx[cb], 0, 0, 0);
            #pragma unroll
            for (int cb = 0; cb < 4; cb++) {
                int feat = cb * 16 + m;
                float bb = bl2[feat];
                #pragma unroll
                for (int r = 0; r < 4; r++)
                    buf[wv][(quad * 4 + r) * 136 + feat] = f2bs(fmaxf(cx[cb][r] + bb, 0.f));
            }
        }
        __builtin_amdgcn_wave_barrier();
        // phase 2: A-frags from buf + s, MFMAs
        short8 a[4];
        a[0] = *(const short8*)&buf[wv][m * 136 + quad * 8];
        a[1] = *(const short8*)&buf[wv][m * 136 + 32 + quad * 8];
        a[2] = *(const short8*)&s[(long)(n0 + m) * 64 + quad * 8];
        a[3] = *(const short8*)&s[(long)(n0 + m) * 64 + 32 + quad * 8];
        __builtin_amdgcn_wave_barrier();   // frag reads complete before buf overwrite
        float4v cz[4], cd[4];
        #pragma unroll
        for (int cb = 0; cb < 4; cb++) {
            cz[cb][0]=0.f; cz[cb][1]=0.f; cz[cb][2]=0.f; cz[cb][3]=0.f;
            cd[cb][0]=0.f; cd[cb][1]=0.f; cd[cb][2]=0.f; cd[cb][3]=0.f;
        }
        #pragma unroll
        for (int ks = 0; ks < 4; ks++)
            #pragma unroll
            for (int cb = 0; cb < 4; cb++)
                cz[cb] = __builtin_amdgcn_mfma_f32_16x16x32_bf16(a[ks], w1f[cb][ks], cz[cb], 0, 0, 0);
        #pragma unroll
        for (int ks = 0; ks < 2; ks++)
            #pragma unroll
            for (int cb = 0; cb < 4; cb++) {
                short8 bg = *(const short8*)&wTg[(cb * 16 + m) * 72 + ks * 32 + quad * 8];
                cd[cb] = __builtin_amdgcn_mfma_f32_16x16x32_bf16(a[2 + ks], bg, cd[cb], 0, 0, 0);
            }
        // phase 3: z|swd into buf (full 128 cols), then wide store
        #pragma unroll
        for (int cb = 0; cb < 4; cb++) {
            int feat = cb * 16 + m;
            #pragma unroll
            for (int r = 0; r < 4; r++) {
                int row = quad * 4 + r;
                buf[wv][row * 136 + feat] = f2bs(cz[cb][r]);
                buf[wv][row * 136 + 64 + feat] = f2bs(cd[cb][r] * dinv[n0 + row]);
            }
        }
        __builtin_amdgcn_wave_barrier();
        uint4* orow = (uint4*)(zsw + (long)n0 * 128);
        #pragma unroll
        for (int it = 0; it < 4; it++) {
            int idx = it * 64 + lane;
            int row = idx >> 4, ch = idx & 15;
            orow[(long)row * 16 + ch] = *(const uint4*)&buf[wv][row * 136 + ch * 8];
        }
        __builtin_amdgcn_wave_barrier();
    }
}

// ---------------- mmC: x'=relu(hB@W2+b2); wout=[x',s]@Whp+bw (f32 direct stores) ----------------
__global__ __launch_bounds__(256) void k_mmC(const bf16* __restrict__ hB,
                                             const bf16* __restrict__ s,
                                             const void* __restrict__ W2,
                                             const void* __restrict__ B2,
                                             const void* __restrict__ Ww,
                                             const void* __restrict__ Bw,
                                             const int* __restrict__ flags,
                                             long w2_off, long b2_off,
                                             float* __restrict__ wout) {
    __shared__ short wT2[64 * 72];
    __shared__ short wTw[64 * 136];
    __shared__ float bl2[64], blw[64];
    __shared__ short xbuf[4][16 * 72];
    const int isf32 = flags[0];
    const int tid = threadIdx.x;
    for (int i = tid; i < 64 * 64; i += 256) {
        int k = i >> 6, f = i & 63;
        wT2[f * 72 + k] = f2bs(ldf(W2, w2_off + i, isf32));
    }
    for (int i = tid; i < 64 * 128; i += 256) {
        int k = i >> 6, f = i & 63;
        wTw[f * 136 + k] = f2bs(ldf(Ww, i, isf32));
    }
    if (tid < 64) { bl2[tid] = ldf(B2, b2_off + tid, isf32); blw[tid] = ldf(Bw, tid, isf32); }
    __syncthreads();

    const int lane = tid & 63, wv = tid >> 6;
    const int m = lane & 15, quad = lane >> 4;

    short8 w2f[4][2], wwf[4][4];
    #pragma unroll
    for (int cb = 0; cb < 4; cb++) {
        #pragma unroll
        for (int ks = 0; ks < 2; ks++)
            w2f[cb][ks] = *(const short8*)&wT2[(cb * 16 + m) * 72 + ks * 32 + quad * 8];
        #pragma unroll
        for (int ks = 0; ks < 4; ks++)
            wwf[cb][ks] = *(const short8*)&wTw[(cb * 16 + m) * 136 + ks * 32 + quad * 8];
    }

    for (int t = blockIdx.x * 4 + wv; t < NTILES; t += gridDim.x * 4) {
        const int n0 = t * 16;
        {
            short8 ah[2];
            ah[0] = *(const short8*)&hB[(long)(n0 + m) * 64 + quad * 8];
            ah[1] = *(const short8*)&hB[(long)(n0 + m) * 64 + 32 + quad * 8];
            float4v cx[4];
            #pragma unroll
            for (int cb = 0; cb < 4; cb++) { cx[cb][0]=0.f; cx[cb][1]=0.f; cx[cb][2]=0.f; cx[cb][3]=0.f; }
            #pragma unroll
            for (int ks = 0; ks < 2; ks++)
                #pragma unroll
                for (int cb = 0; cb < 4; cb++)
                    cx[cb] = __builtin_amdgcn_mfma_f32_16x16x32_bf16(ah[ks], w2f[cb][ks], cx[cb], 0, 0, 0);
            #pragma unroll
            for (int cb = 0; cb < 4; cb++) {
                int feat = cb * 16 + m;
                float bb = bl2[feat];
                #pragma unroll
                for (int r = 0; r < 4; r++)
                    xbuf[wv][(quad * 4 + r) * 72 + feat] = f2bs(fmaxf(cx[cb][r] + bb, 0.f));
            }
        }
        __builtin_amdgcn_wave_barrier();
        {
            short8 a[4];
            a[0] = *(const short8*)&xbuf[wv][m * 72 + quad * 8];
            a[1] = *(const short8*)&xbuf[wv][m * 72 + 32 + quad * 8];
            a[2] = *(const short8*)&s[(long)(n0 + m) * 64 + quad * 8];
            a[3] = *(const short8*)&s[(long)(n0 + m) * 64 + 32 + quad * 8];
            float4v cz[4];
            #pragma unroll
            for (int cb = 0; cb < 4; cb++) { cz[cb][0]=0.f; cz[cb][1]=0.f; cz[cb][2]=0.f; cz[cb][3]=0.f; }
            #pragma unroll
            for (int ks = 0; ks < 4; ks++)
                #pragma unroll
                for (int cb = 0; cb < 4; cb++)
                    cz[cb] = __builtin_amdgcn_mfma_f32_16x16x32_bf16(a[ks], wwf[cb][ks], cz[cb], 0, 0, 0);
            #pragma unroll
            for (int cb = 0; cb < 4; cb++) {
                int feat = cb * 16 + m;
                float bw = blw[feat];
                #pragma unroll
                for (int r = 0; r < 4; r++)
                    wout[(long)(n0 + quad * 4 + r) * 64 + feat] = cz[cb][r] + bw;
            }
        }
        __builtin_amdgcn_wave_barrier();
    }
}

// ---------------- fused GIN+GCN gather, 4 rows per memory instruction ----------------
__global__ __launch_bounds__(256) void k_gather4(const uint* __restrict__ zsw,
                                                 const int* __restrict__ row_end,
                                                 const int* __restrict__ deg,
                                                 const int* __restrict__ csr_src,
                                                 const void* __restrict__ b1,
                                                 const void* __restrict__ bg,
                                                 const float* __restrict__ dinv,
                                                 const int* __restrict__ flags,
                                                 long b_off,
                                                 uint* __restrict__ hB,
                                                 uint* __restrict__ sOut) {
    int tid = threadIdx.x;
    int wv = tid >> 6, lane = tid & 63;
    int grp = lane >> 4, sub = lane & 15;
    int n = blockIdx.x * 4 + wv;
    if (n >= N_NODES) return;
    int end = row_end[n], dg = deg[n];
    int beg = end - dg;
    int R = dg + 1;                         // rows incl. self (idx 0)
    const uint4* zp = (const uint4*)zsw;
    float a[8];
    #pragma unroll
    for (int j = 0; j < 8; j++) a[j] = 0.f;
    for (int i = 0; i < R; i += 8) {
        int iA = i + grp, iB = i + 4 + grp;
        uint4 uA = {0, 0, 0, 0}, uB = {0, 0, 0, 0};
        if (iA < R) {
            int sA = (iA == 0) ? n : csr_src[beg + iA - 1];
            uA = zp[(long)sA * 16 + sub];
        }
        if (iB < R) {
            int sB = csr_src[beg + iB - 1];
            uB = zp[(long)sB * 16 + sub];
        }
        a[0] += bflo(uA.x) + bflo(uB.x);
        a[1] += bfhi(uA.x) + bfhi(uB.x);
        a[2] += bflo(uA.y) + bflo(uB.y);
        a[3] += bfhi(uA.y) + bfhi(uB.y);
        a[4] += bflo(uA.z) + bflo(uB.z);
        a[5] += bfhi(uA.z) + bfhi(uB.z);
        a[6] += bflo(uA.w) + bflo(uB.w);
        a[7] += bfhi(uA.w) + bfhi(uB.w);
    }
    #pragma unroll
    for (int j = 0; j < 8; j++) {
        a[j] += __shfl_xor(a[j], 16);
        a[j] += __shfl_xor(a[j], 32);
    }
    int q = 4 * sub + grp;
    float v0 = a[2 * grp], v1 = a[2 * grp + 1];
    int isf32 = flags[0];
    if (q < 32) {
        float c0 = ldf(b1, b_off + 2 * q, isf32);
        float c1 = ldf(b1, b_off + 2 * q + 1, isf32);
        hB[(long)n * 32 + q] = packbf(fmaxf(v0 + c0, 0.f), fmaxf(v1 + c1, 0.f));
    } else {
        int qq = q - 32;
        float c0 = ldf(bg, b_off + 2 * qq, isf32);
        float c1 = ldf(bg, b_off + 2 * qq + 1, isf32);
        float dn = dinv[n];
        sOut[(long)n * 32 + qq] = packbf(tanhf(dn * v0 + c0), tanhf(dn * v1 + c1));
    }
}

// ---------------- pool: run-length segmented sum over sorted batch ----------------
__global__ __launch_bounds__(256) void k_pool(const float* __restrict__ xw,
                                              const int* __restrict__ batch,
                                              const int* __restrict__ flags,
                                              float* __restrict__ xp) {
    int tid = threadIdx.x;
    int slot = tid >> 6, lane = tid & 63;
    int nbeg = (blockIdx.x * 4 + slot) * 16;
    if (nbeg >= N_NODES) return;
    int nend = nbeg + 16;
    if (nend > N_NODES) nend = N_NODES;
    int i64 = flags[1];
    int g = geti(batch, nbeg, i64);
    float acc = 0.f;
    for (int n = nbeg; n < nend; n++) {
        int gn = geti(batch, n, i64);
        if (gn != g) { atomicAdd(&xp[(long)g * 64 + lane], acc); acc = 0.f; g = gn; }
        acc += xw[(long)n * 64 + lane];
    }
    atomicAdd(&xp[(long)g * 64 + lane], acc);
}

// ---------------- final: post + readout + log_softmax ----------------
__global__ __launch_bounds__(64) void k_final(const float* __restrict__ xp,
                                              const void* __restrict__ post_w,
                                              const void* __restrict__ post_b,
                                              const void* __restrict__ ro_w,
                                              const void* __restrict__ ro_b,
                                              const int* __restrict__ flags,
                                              void* __restrict__ out) {
    __shared__ float h2[64];
    __shared__ float lg[16];
    int isf32 = flags[0];
    int g = blockIdx.x;
    int f = threadIdx.x;
    float xr = xp[(long)g * 64 + f];
    float acc = ldf(post_b, f, isf32);
    #pragma unroll
    for (int j = 0; j < 64; j++) acc += __shfl(xr, j) * ldf(post_w, j * 64 + f, isf32);
    float v = fmaxf(acc, 0.f);
    h2[f] = v;
    long oxp = (long)g * 64 + f;
    if (isf32) ((float*)out)[oxp] = v; else ((bf16*)out)[oxp] = f2b(v);
    __syncthreads();
    if (f < 16) {
        float a = ldf(ro_b, f, isf32);
        for (int j = 0; j < 64; j++) a += h2[j] * ldf(ro_w, j * 16 + f, isf32);
        lg[f] = a;
    }
    __syncthreads();
    if (f < 16) {
        float m = -1e30f;
        for (int j = 0; j < 16; j++) m = fmaxf(m, lg[j]);
        float sum = 0.f;
        for (int j = 0; j < 16; j++) sum += expf(lg[j] - m);
        long oy = (long)N_GRAPHS * 64 + (long)g * 16 + f;
        float yv = lg[f] - m - logf(sum);
        if (isf32) ((float*)out)[oy] = yv; else ((bf16*)out)[oy] = f2b(yv);
    }
}

extern "C" void kernel_launch(void* const* d_in, const int* in_sizes, int n_in,
                              void* d_out, int out_size, void* d_ws, size_t ws_size,
                              hipStream_t stream) {
    const void* x_in  = d_in[0];
    const void* s_in  = d_in[1];
    const int*  ei    = (const int*)d_in[2];
    const int*  batch = (const int*)d_in[3];
    const void* pre_w = d_in[4];
    const void* pre_b = d_in[5];
    const void* emb_w = d_in[6];
    const void* emb_b = d_in[7];
    const void* gin_w1 = d_in[8];
    const void* gin_b1 = d_in[9];
    const void* gin_w2 = d_in[10];
    const void* gin_b2 = d_in[11];
    const void* gcn_w  = d_in[12];
    const void* gcn_b  = d_in[13];
    const void* whp_w  = d_in[14];
    const void* whp_b  = d_in[15];
    const void* post_w = d_in[16];
    const void* post_b = d_in[17];
    const void* ro_w   = d_in[18];
    const void* ro_b   = d_in[19];

    int* flags   = (int*)d_ws;
    int* deg     = flags + 64;
    int* row_end = deg + N_NODES;
    int* hist    = row_end + N_NODES;
    int* pexcl   = hist + NB1 * NBUCK;
    int* total   = pexcl + NB1 * NBUCK;
    int* bbase   = total + NBUCK;
    uint* bstore = (uint*)(bbase + NBUCK + 4);
    int* csr_src = (int*)(bstore + N_EDGES);
    float* dinv  = (float*)(csr_src + N_EDGES);
    bf16* x0     = (bf16*)(dinv + N_NODES);
    bf16* sA     = x0 + (long)N_NODES * 64;
    bf16* hB     = sA + (long)N_NODES * 64;
    uint* zsw    = (uint*)(hB + (long)N_NODES * 64);
    float* wout  = (float*)(zsw + (long)N_NODES * 64);
    float* xp    = wout + (long)N_NODES * 64;

    const int MMB = 512;
    const int GGB = (N_NODES + 3) / 4;       // 25000

    k_detect<<<1, 64, 0, stream>>>(x_in, ei, flags);

    // CSR + deg + dinv + row_end: two-pass radix partition
    k1_hist<<<NB1, 256, 0, stream>>>(ei, flags, hist);
    k2a<<<NBUCK, 256, 0, stream>>>(hist, pexcl, total);
    k2b<<<1, 256, 0, stream>>>(total, bbase);
    k3_scatter<<<NB1, 256, 0, stream>>>(ei, flags, pexcl, bbase, bstore);
    k4_csr<<<NBUCK, 256, 0, stream>>>(bstore, bbase, deg, dinv, row_end, csr_src);

    const long W1 = 128 * 64, W2 = 64 * 64, WG = 64 * 64, B = 64;

    // pre / embedding -> bf16 activations
    k_mm_in<128, 128><<<MMB, 256, 0, stream>>>(x_in, pre_w, pre_b, flags, x0);
    k_mm_in<32, 16><<<MMB, 256, 0, stream>>>(s_in, emb_w, emb_b, flags, sA);

    // ---- layer 0 ----
    k_mmA<<<MMB, 256, 0, stream>>>(x0, sA, gin_w1, gcn_w, dinv, flags, 0L, 0L, (bf16*)zsw);
    k_gather4<<<GGB, 256, 0, stream>>>(zsw, row_end, deg, csr_src, gin_b1, gcn_b, dinv, flags, 0L, (uint*)hB, (uint*)sA);

    // ---- layer 0 tail fused with layer 1 head ----
    k_mmB<<<MMB, 256, 0, stream>>>(hB, sA, gin_w2, gin_b2, gin_w1, gcn_w, dinv, flags,
                                   0L, 0L, W1, WG, (bf16*)zsw);
    k_gather4<<<GGB, 256, 0, stream>>>(zsw, row_end, deg, csr_src, gin_b1, gcn_b, dinv, flags, B, (uint*)hB, (uint*)sA);

    // ---- layer 1 tail + whp -> wout; pool; final ----
    k_mmC<<<MMB, 256, 0, stream>>>(hB, sA, gin_w2, gin_b2, whp_w, whp_b, flags, W2, B, wout);
    hipMemsetAsync(xp, 0, (size_t)N_GRAPHS * 64 * sizeof(float), stream);
    k_pool<<<(N_NODES + 63) / 64, 256, 0, stream>>>(wout, batch, flags, xp);

    k_final<<<N_GRAPHS, 64, 0, stream>>>(xp, post_w, post_b, ro_w, ro_b, flags, d_out);
}